// Round 8
// baseline (54.382 us; speedup 1.0000x reference)
//
#include <hip/hip_runtime.h>

#define B_ 32
#define T_ 8192
#define F_ 256
#define H_ 128

typedef short bf16x8 __attribute__((ext_vector_type(8)));
typedef float f32x4  __attribute__((ext_vector_type(4)));

// Hardware packed f32->bf16 RNE conversion (1 VALU op for 2 values).
static __device__ __forceinline__ unsigned int pack_bf2(float lo, float hi) {
    unsigned int r;
    asm("v_cvt_pk_bf16_f32 %0, %1, %2" : "=v"(r) : "v"(lo), "v"(hi));
    return r;
}

// tanh(x) = 1 - 2/(e^{2x}+1) via v_exp_f32 (exp2). No clamp needed:
// e^{+inf}=inf -> rcp=0 -> 1; e^{-inf}=0 -> 1-2 = -1. |err| ~1e-6.
static __device__ __forceinline__ float fast_tanh(float x) {
    float e = __builtin_amdgcn_exp2f(x * 2.8853900817779268f);  // e^{2x}
    return 1.f - 2.f * __builtin_amdgcn_rcpf(e + 1.f);
}

// Single fused kernel: 512 blocks x 512 threads (8 waves).
// Block -> (b = blk>>4, t0 = (blk&15)*512); 16 half-tiles of 32 rows.
// Wave w owns ntile w (h-columns [16w,16w+16)), W1 frags in registers (32 VGPR).
// DEPTH-2 REGISTER PREFETCH: two statically-indexed buffers xa (even half-
// tiles -> LDS buf0) and xb (odd -> buf1); global loads are issued 2 iters
// ahead, giving ~2 compute phases of in-flight time to cover HBM/L3 latency.
// Barrier is raw s_barrier + lgkmcnt(0) ONLY (no vmcnt drain) so those loads
// stay in flight across barriers; compiler inserts counted vmcnt at pack.
// Race analysis (1 barrier/iter): writes to buf[p] at step i+2 occur after
// barrier(i+1); all reads of buf[p] at step i complete before any wave
// reaches barrier(i+1). Safe.
// NOTE: no min-waves bound (round 5: forcing VGPR<=128 spilled, 60->106 us).
__global__ __launch_bounds__(512) void attn_fused(const float* __restrict__ enc,
                                                  const float* __restrict__ dec,
                                                  const float* __restrict__ W1,
                                                  const float* __restrict__ W2,
                                                  const float* __restrict__ Vvec,
                                                  float* __restrict__ out) {
    __shared__ __align__(16) unsigned char tile_lds[2][32 * 512]; // 2 x 16 KB
    __shared__ float red[8][512];    // 16 KB: per-wave row partials
    __shared__ float w2dp[4][128];   // w2d partial sums
    __shared__ float w2dv[128];      // w2d[b][:]

    const int tid  = threadIdx.x;
    const int blk  = blockIdx.x;
    const int b    = blk >> 4;
    const int t0   = (blk & 15) << 9;
    const int w    = tid >> 6;
    const int lane = tid & 63;
    const int q    = lane >> 4;     // A: k-quarter; D: row-group
    const int c    = lane & 15;     // A: row-in-tile16; D: col-in-ntile

    const f32x4* src = (const f32x4*)(enc + ((size_t)b * T_ + t0) * F_);

    // ---- issue half-tiles 0 and 1 loads first: latency overlaps setup ----
    f32x4 xa[4], xb[4];
    #pragma unroll
    for (int i = 0; i < 4; ++i) xa[i] = src[i * 512 + tid];
    #pragma unroll
    for (int i = 0; i < 4; ++i) xb[i] = src[2048 + i * 512 + tid];

    // ---- W1 -> B-fragments in registers (wave w owns ntile w) ----
    const int h = 16 * w + c;
    bf16x8 bw[8];
    #pragma unroll
    for (int ks = 0; ks < 8; ++ks) {
        const float* wp = W1 + (64 * q + 8 * ks) * H_ + h;
        union { bf16x8 v; unsigned int u[4]; } pk;
        #pragma unroll
        for (int jj = 0; jj < 4; ++jj)
            pk.u[jj] = pack_bf2(wp[(2 * jj) * H_], wp[(2 * jj + 1) * H_]);
        bw[ks] = pk.v;
    }

    // ---- w2d[b][hh] = dec[b]@W2[:,hh], 4-way f-split (fp32 exact) ----
    {
        const int hh = tid & 127, p = tid >> 7;
        const float* dp  = dec + b * F_ + p * 64;      // uniform -> scalar loads
        const float* w2p = W2 + (p * 64) * H_ + hh;    // coalesced per f
        float s = 0.f;
        #pragma unroll 8
        for (int f = 0; f < 64; ++f) s += dp[f] * w2p[f * H_];
        w2dp[p][hh] = s;
    }
    __syncthreads();
    if (tid < 128)
        w2dv[tid] = w2dp[0][tid] + w2dp[1][tid] + w2dp[2][tid] + w2dp[3][tid];
    __syncthreads();

    const float Vv = Vvec[h];
    const float wd = w2dv[h];
    const int sw = c & 7;

// pack register half-tile X into LDS buffer BUF (cvt_pk + XOR swizzle)
#define STAGE(X, BUF)                                                        \
    {                                                                        \
        unsigned char* buf_ = (BUF);                                         \
        _Pragma("unroll")                                                    \
        for (int i = 0; i < 4; ++i) {                                        \
            const int flat4 = i * 512 + tid;                                 \
            const int row   = flat4 >> 6;                                    \
            const int c4    = flat4 & 63;                                    \
            const int chunk = (c4 >> 1) ^ (row & 7);                         \
            uint2 v;                                                         \
            v.x = pack_bf2((X)[i][0], (X)[i][1]);                            \
            v.y = pack_bf2((X)[i][2], (X)[i][3]);                            \
            *(uint2*)(buf_ + row * 512 + chunk * 16 + (c4 & 1) * 8) = v;     \
        }                                                                    \
    }

// issue global loads for half-tile HT into X (registers; no wait here)
#define ISSUE(X, HT)                                                         \
    {                                                                        \
        const f32x4* sp_ = src + (HT) * 2048;                                \
        _Pragma("unroll")                                                    \
        for (int i = 0; i < 4; ++i) (X)[i] = sp_[i * 512 + tid];             \
    }

// compute half-tile HT from LDS buffer BUF
#define COMPUTE(BUF, HT)                                                     \
    {                                                                        \
        const unsigned char* bb_ = (BUF);                                    \
        _Pragma("unroll")                                                    \
        for (int g = 0; g < 2; ++g) {                                        \
            const unsigned char* rbase = bb_ + (g * 16 + c) * 512;           \
            f32x4 acc = {0.f, 0.f, 0.f, 0.f};                                \
            _Pragma("unroll")                                                \
            for (int ks = 0; ks < 8; ++ks) {                                 \
                bf16x8 a = *(const bf16x8*)(rbase + ((8 * q + ks) ^ sw) * 16);\
                acc = __builtin_amdgcn_mfma_f32_16x16x32_bf16(a, bw[ks], acc, 0, 0, 0);\
            }                                                                \
            f32x4 part;                                                      \
            _Pragma("unroll")                                                \
            for (int r = 0; r < 4; ++r)                                      \
                part[r] = Vv * fast_tanh(acc[r] + wd);                       \
            _Pragma("unroll")                                                \
            for (int m = 1; m < 16; m <<= 1) {                               \
                _Pragma("unroll")                                            \
                for (int r = 0; r < 4; ++r) part[r] += __shfl_xor(part[r], m, 64);\
            }                                                                \
            if (c == 0)                                                      \
                *(f32x4*)&red[w][(HT) * 32 + g * 16 + 4 * q] = part;         \
        }                                                                    \
    }

#define BARRIER() asm volatile("s_waitcnt lgkmcnt(0)\n\ts_barrier" ::: "memory")

    for (int it = 0; it < 8; ++it) {
        const int ht0 = 2 * it;
        // even half-tile: xa -> buf0
        STAGE(xa, tile_lds[0]);
        if (it < 7) ISSUE(xa, ht0 + 2);
        BARRIER();
        COMPUTE(tile_lds[0], ht0);
        // odd half-tile: xb -> buf1
        STAGE(xb, tile_lds[1]);
        if (it < 7) ISSUE(xb, ht0 + 3);
        BARRIER();
        COMPUTE(tile_lds[1], ht0 + 1);
    }

#undef STAGE
#undef ISSUE
#undef COMPUTE
#undef BARRIER

    __syncthreads();
    // ---- combine 8 wave-partials for all 512 rows, coalesced store ----
    float s = 0.f;
    #pragma unroll
    for (int ww = 0; ww < 8; ++ww) s += red[ww][tid];
    out[(size_t)b * T_ + t0 + tid] = s;
}

extern "C" void kernel_launch(void* const* d_in, const int* in_sizes, int n_in,
                              void* d_out, int out_size, void* d_ws, size_t ws_size,
                              hipStream_t stream) {
    const float* enc = (const float*)d_in[0];
    const float* dec = (const float*)d_in[1];
    const float* W1  = (const float*)d_in[2];
    const float* W2  = (const float*)d_in[3];
    const float* V   = (const float*)d_in[4];
    float* out = (float*)d_out;

    attn_fused<<<512, 512, 0, stream>>>(enc, dec, W1, W2, V, out);
}

// Round 9
// 49.270 us; speedup vs baseline: 1.1037x; 1.1037x over previous
//
#include <hip/hip_runtime.h>

#define B_ 32
#define T_ 8192
#define F_ 256
#define H_ 128

typedef short bf16x8 __attribute__((ext_vector_type(8)));
typedef float f32x4  __attribute__((ext_vector_type(4)));

// Hardware packed f32->bf16 RNE conversion (1 VALU op for 2 values).
static __device__ __forceinline__ unsigned int pack_bf2(float lo, float hi) {
    unsigned int r;
    asm("v_cvt_pk_bf16_f32 %0, %1, %2" : "=v"(r) : "v"(lo), "v"(hi));
    return r;
}

// tanh(x) = 1 - 2/(e^{2x}+1) via v_exp_f32 (exp2). No clamp needed:
// e^{+inf}=inf -> rcp=0 -> 1; e^{-inf}=0 -> 1-2 = -1. |err| ~1e-6.
static __device__ __forceinline__ float fast_tanh(float x) {
    float e = __builtin_amdgcn_exp2f(x * 2.8853900817779268f);  // e^{2x}
    return 1.f - 2.f * __builtin_amdgcn_rcpf(e + 1.f);
}

// Single fused kernel: 512 blocks x 512 threads (8 waves).
// Block -> (b = blk>>4, t0 = (blk&15)*512); 16 half-tiles of 32 rows.
//
// SWAPPED-OPERAND MFMA (round 9): D = W1^T * enc^T instead of enc * W1.
//   A-operand = bw (W1 frags; register contents IDENTICAL to rounds 6-8,
//   just consumed in the A slot: A[row=c][k=8q+j] = W1[f=64q+8ks+j][16w+c]).
//   B-operand = enc tile from LDS, same ds_read pattern as before
//   (B[k=8q+j][col=c] = enc[t=c][f=64q+8ks+j]).
//   D[row = h_local = 4q+r][col = t = c]: the V-dot over h is now 4 in-lane
//   FMAs + TWO shfl_xor stages (16, 32) instead of 16 shfls per g — 8x
//   fewer DS-pipe ops in the reduction (the round-8 analysis showed the
//   butterfly was ~2000 cyc/half-tile/CU of LDS-pipe time).
// f-permutation note: A and B agree that slot (q, j) of mfma #ks holds
// global f = 64q + 8ks + j, so the K-sum is correct (sum over all 256 f).
//
// Barrier is raw s_barrier + lgkmcnt(0) ONLY (no vmcnt drain) so prefetch
// loads stay in flight across barriers. Depth-2 prefetch xa/xb, statically
// indexed (rule #20). Race analysis: writes to buf[p] at step i+2 occur
// after barrier(i+1); reads of buf[p] at step i complete before any wave
// reaches barrier(i+1). Safe.
// NOTE: no min-waves bound (round 5: forcing VGPR<=128 spilled, 60->106 us).
__global__ __launch_bounds__(512) void attn_fused(const float* __restrict__ enc,
                                                  const float* __restrict__ dec,
                                                  const float* __restrict__ W1,
                                                  const float* __restrict__ W2,
                                                  const float* __restrict__ Vvec,
                                                  float* __restrict__ out) {
    __shared__ __align__(16) unsigned char tile_lds[2][32 * 512]; // 2 x 16 KB
    __shared__ float red[8][512];    // 16 KB: per-wave row partials
    __shared__ float w2dp[4][128];   // w2d partial sums
    __shared__ float w2dv[128];      // w2d[b][:]

    const int tid  = threadIdx.x;
    const int blk  = blockIdx.x;
    const int b    = blk >> 4;
    const int t0   = (blk & 15) << 9;
    const int w    = tid >> 6;
    const int lane = tid & 63;
    const int q    = lane >> 4;     // k-quarter; D: h-row-group
    const int c    = lane & 15;     // B: t-col; A: h-row

    const f32x4* src = (const f32x4*)(enc + ((size_t)b * T_ + t0) * F_);

    // ---- issue half-tiles 0 and 1 loads first: latency overlaps setup ----
    f32x4 xa[4], xb[4];
    #pragma unroll
    for (int i = 0; i < 4; ++i) xa[i] = src[i * 512 + tid];
    #pragma unroll
    for (int i = 0; i < 4; ++i) xb[i] = src[2048 + i * 512 + tid];

    // ---- W1 -> fragments in registers (wave w owns h-ntile w) ----
    // bw[ks][j] = bf16(W1[64q + 8ks + j][16w + c]) — consumed as A-operand.
    const int h = 16 * w + c;
    bf16x8 bw[8];
    #pragma unroll
    for (int ks = 0; ks < 8; ++ks) {
        const float* wp = W1 + (64 * q + 8 * ks) * H_ + h;
        union { bf16x8 v; unsigned int u[4]; } pk;
        #pragma unroll
        for (int jj = 0; jj < 4; ++jj)
            pk.u[jj] = pack_bf2(wp[(2 * jj) * H_], wp[(2 * jj + 1) * H_]);
        bw[ks] = pk.v;
    }

    // ---- w2d[b][hh] = dec[b]@W2[:,hh], 4-way f-split (fp32 exact) ----
    {
        const int hh = tid & 127, p = tid >> 7;
        const float* dp  = dec + b * F_ + p * 64;      // uniform -> scalar loads
        const float* w2p = W2 + (p * 64) * H_ + hh;    // coalesced per f
        float s = 0.f;
        #pragma unroll 8
        for (int f = 0; f < 64; ++f) s += dp[f] * w2p[f * H_];
        w2dp[p][hh] = s;
    }
    __syncthreads();
    if (tid < 128)
        w2dv[tid] = w2dp[0][tid] + w2dp[1][tid] + w2dp[2][tid] + w2dp[3][tid];
    __syncthreads();

    // Per-lane epilogue constants for D rows h = 16w + 4q + r, r=0..3
    float Vv4[4], wd4[4];
    #pragma unroll
    for (int r = 0; r < 4; ++r) {
        const int hr = 16 * w + 4 * q + r;
        Vv4[r] = Vvec[hr];
        wd4[r] = w2dv[hr];
    }
    const int sw = c & 7;

// pack register half-tile X into LDS buffer BUF (cvt_pk + XOR swizzle)
#define STAGE(X, BUF)                                                        \
    {                                                                        \
        unsigned char* buf_ = (BUF);                                         \
        _Pragma("unroll")                                                    \
        for (int i = 0; i < 4; ++i) {                                        \
            const int flat4 = i * 512 + tid;                                 \
            const int row   = flat4 >> 6;                                    \
            const int c4    = flat4 & 63;                                    \
            const int chunk = (c4 >> 1) ^ (row & 7);                         \
            uint2 v;                                                         \
            v.x = pack_bf2((X)[i][0], (X)[i][1]);                            \
            v.y = pack_bf2((X)[i][2], (X)[i][3]);                            \
            *(uint2*)(buf_ + row * 512 + chunk * 16 + (c4 & 1) * 8) = v;     \
        }                                                                    \
    }

// issue global loads for half-tile HT into X (registers; no wait here)
#define ISSUE(X, HT)                                                         \
    {                                                                        \
        const f32x4* sp_ = src + (HT) * 2048;                                \
        _Pragma("unroll")                                                    \
        for (int i = 0; i < 4; ++i) (X)[i] = sp_[i * 512 + tid];             \
    }

// compute half-tile HT from LDS buffer BUF (swapped-operand MFMA)
#define COMPUTE(BUF, HT)                                                     \
    {                                                                        \
        const unsigned char* bb_ = (BUF);                                    \
        _Pragma("unroll")                                                    \
        for (int g = 0; g < 2; ++g) {                                        \
            const unsigned char* rbase = bb_ + (g * 16 + c) * 512;           \
            f32x4 acc = {0.f, 0.f, 0.f, 0.f};                                \
            _Pragma("unroll")                                                \
            for (int ks = 0; ks < 8; ++ks) {                                 \
                bf16x8 be = *(const bf16x8*)(rbase + ((8 * q + ks) ^ sw) * 16);\
                acc = __builtin_amdgcn_mfma_f32_16x16x32_bf16(bw[ks], be, acc, 0, 0, 0);\
            }                                                                \
            float part = Vv4[0] * fast_tanh(acc[0] + wd4[0])                 \
                       + Vv4[1] * fast_tanh(acc[1] + wd4[1])                 \
                       + Vv4[2] * fast_tanh(acc[2] + wd4[2])                 \
                       + Vv4[3] * fast_tanh(acc[3] + wd4[3]);                \
            part += __shfl_xor(part, 16, 64);                                \
            part += __shfl_xor(part, 32, 64);                                \
            if (lane < 16)                                                   \
                red[w][(HT) * 32 + g * 16 + lane] = part;                    \
        }                                                                    \
    }

#define BARRIER() asm volatile("s_waitcnt lgkmcnt(0)\n\ts_barrier" ::: "memory")

    for (int it = 0; it < 8; ++it) {
        const int ht0 = 2 * it;
        // even half-tile: xa -> buf0
        STAGE(xa, tile_lds[0]);
        if (it < 7) ISSUE(xa, ht0 + 2);
        BARRIER();
        COMPUTE(tile_lds[0], ht0);
        // odd half-tile: xb -> buf1
        STAGE(xb, tile_lds[1]);
        if (it < 7) ISSUE(xb, ht0 + 3);
        BARRIER();
        COMPUTE(tile_lds[1], ht0 + 1);
    }

#undef STAGE
#undef ISSUE
#undef COMPUTE
#undef BARRIER

    __syncthreads();
    // ---- combine 8 wave-partials for all 512 rows, coalesced store ----
    float s = 0.f;
    #pragma unroll
    for (int ww = 0; ww < 8; ++ww) s += red[ww][tid];
    out[(size_t)b * T_ + t0 + tid] = s;
}

extern "C" void kernel_launch(void* const* d_in, const int* in_sizes, int n_in,
                              void* d_out, int out_size, void* d_ws, size_t ws_size,
                              hipStream_t stream) {
    const float* enc = (const float*)d_in[0];
    const float* dec = (const float*)d_in[1];
    const float* W1  = (const float*)d_in[2];
    const float* W2  = (const float*)d_in[3];
    const float* V   = (const float*)d_in[4];
    float* out = (float*)d_out;

    attn_fused<<<512, 512, 0, stream>>>(enc, dec, W1, W2, V, out);
}